// Round 5
// baseline (839.837 us; speedup 1.0000x reference)
//
#include <hip/hip_runtime.h>
#include <hip/hip_bf16.h>

// ---------------------------------------------------------------------------
// HazardGNN round 5: edge/head kernels shrink LDS (x-slab 336->272 B/row) by
// handling edge-attr via a register-built A-fragment MFMA (weight image is
// zero-padded past k=132, so garbage lanes annihilate). 3 blocks/CU instead
// of 2. GRU zeroes its own agg rows for the next layer (drops 2 memsets).
// ---------------------------------------------------------------------------

typedef __attribute__((ext_vector_type(8))) short bf16x8;
typedef __attribute__((ext_vector_type(4))) float f32x4;
#define MFMA16(a, b, c) __builtin_amdgcn_mfma_f32_16x16x32_bf16(a, b, c, 0, 0, 0)

#define CHUNK 128
#define XSTRIDE 272   // bytes per x row: 128 (h_src) + 128 (h_dst) + 16 pad
#define MSTRIDE 264   // bytes per m row: 66 f32 (aliases x slab)
#define HSTRIDE 144   // bytes per hid row: 72 bf16
#define SLABSZ 8704   // 32 * XSTRIDE
#define HIDSZ  4608   // 32 * HSTRIDE
// edge/head LDS: 4*8704 + 4*4608 = 53248 B -> 3 blocks/CU

// GRU LDS strides (+8 bf16 pad to break power-of-2 banking)
#define WRZST 264     // 128 bf16 + 4 pad
#define WNST  136     // 64 bf16 + 4 pad

__device__ __forceinline__ float fast_sig(float x) { return 1.f / (1.f + __expf(-x)); }
__device__ __forceinline__ float fast_tanh(float x) {
    float ax = fabsf(x);
    float t = __expf(-2.f * ax);
    return copysignf((1.f - t) / (1.f + t), x);
}
__device__ __forceinline__ ushort f2bf(float f) {  // RNE fp32->bf16
    unsigned u = __float_as_uint(f);
    unsigned r = u + 0x7FFF + ((u >> 16) & 1);
    return (ushort)(r >> 16);
}

// ---------------------------------------------------------------------------
// prep: bf16 weight images (row-major [out][K], K padded to 160 with zeros)
// + stacked GRU weights.
// ---------------------------------------------------------------------------
__global__ void prep_kernel(const float* __restrict__ msg_w1,
                            const float* __restrict__ msg_w2,
                            const float* __restrict__ gru_wih,
                            const float* __restrict__ gru_whh,
                            const float* __restrict__ head_w1,
                            const float* __restrict__ head_w2,
                            ushort* __restrict__ Wb1, ushort* __restrict__ Wb2,
                            ushort* __restrict__ Wh1, ushort* __restrict__ Wh2b,
                            ushort* __restrict__ Wrz, ushort* __restrict__ Wni,
                            ushort* __restrict__ Wnh) {
    int t = blockIdx.x * 256 + threadIdx.x;
    if (t < 30720) {  // Wb1[l][j][k<160]
        int l = t / 10240, r = t % 10240, j = r / 160, k = r % 160;
        Wb1[t] = (k < 132) ? f2bf(msg_w1[l * 8448 + j * 132 + k]) : 0;
        return;
    }
    t -= 30720;
    if (t < 12288) {  // Wb2[l][j][k<64]
        Wb2[t] = f2bf(msg_w2[t]);
        return;
    }
    t -= 12288;
    if (t < 10240) {  // Wh1[j][k<160]
        int j = t / 160, k = t % 160;
        Wh1[t] = (k < 132) ? f2bf(head_w1[j * 132 + k]) : 0;
        return;
    }
    t -= 10240;
    if (t < 1024) {  // Wh2b[16][64]: row 0 = head_w2, rows 1..15 zero
        int j = t >> 6, k = t & 63;
        Wh2b[t] = (j == 0) ? f2bf(head_w2[k]) : 0;
        return;
    }
    t -= 1024;
    if (t < 49152) {  // Wrz[l][n][k]: k<64 wih, k>=64 whh
        int l = t / 16384, r = t % 16384, n = r >> 7, k = r & 127;
        float v = (k < 64) ? gru_wih[l * 12288 + n * 64 + k]
                           : gru_whh[l * 12288 + n * 64 + (k - 64)];
        Wrz[t] = f2bf(v);
        return;
    }
    t -= 49152;
    if (t < 12288) {  // Wni[l][j][k]
        int l = t / 4096, r = t % 4096, j = r >> 6, k = r & 63;
        Wni[t] = f2bf(gru_wih[l * 12288 + (128 + j) * 64 + k]);
        return;
    }
    t -= 12288;
    if (t < 12288) {  // Wnh[l][j][k]
        int l = t / 4096, r = t % 4096, j = r >> 6, k = r & 63;
        Wnh[t] = f2bf(gru_whh[l * 12288 + (128 + j) * 64 + k]);
    }
}

// h (fp32) + hb (bf16 mirror) from embedding
__global__ void embed_kernel(float* __restrict__ h, ushort* __restrict__ hb,
                             const float* __restrict__ emb,
                             const int* __restrict__ kinds, int N) {
    int t = blockIdx.x * 256 + threadIdx.x;
    if (t >= N * 64) return;
    int node = t >> 6, d = t & 63;
    float v = emb[kinds[node] * 64 + d];
    h[t] = v;
    hb[t] = f2bf(v);
}

// -------------------- counting sort by dst --------------------
__global__ void hist_kernel(const int* __restrict__ dst, int* __restrict__ deg, int E) {
    int e = blockIdx.x * 256 + threadIdx.x;
    if (e < E) atomicAdd(&deg[dst[e]], 1);
}

__global__ void scan_kernel(const int* __restrict__ deg, int* __restrict__ cursor, int N) {
    __shared__ int sums[1024];
    int tid = threadIdx.x;
    int chunk = (N + 1023) >> 10;
    int lo = tid * chunk, hi = min(lo + chunk, N);
    int s = 0;
    for (int i = lo; i < hi; i++) s += deg[i];
    sums[tid] = s;
    __syncthreads();
    for (int off = 1; off < 1024; off <<= 1) {
        int v = (tid >= off) ? sums[tid - off] : 0;
        __syncthreads();
        sums[tid] += v;
        __syncthreads();
    }
    int run = (tid > 0) ? sums[tid - 1] : 0;
    for (int i = lo; i < hi; i++) {
        cursor[i] = run;
        run += deg[i];
    }
}

__global__ void scatter_kernel(const int* __restrict__ src, const int* __restrict__ dst,
                               const float* __restrict__ ea, int* __restrict__ cursor,
                               int* __restrict__ src_s, int* __restrict__ dst_s,
                               ushort* __restrict__ ea_sb, int E) {
    int e = blockIdx.x * 256 + threadIdx.x;
    if (e >= E) return;
    int d = dst[e];
    int p = atomicAdd(&cursor[d], 1);
    src_s[p] = src[e];
    dst_s[p] = d;
    float4 e4 = ((const float4*)ea)[e];
    ushort4 eb;
    eb.x = f2bf(e4.x); eb.y = f2bf(e4.y); eb.z = f2bf(e4.z); eb.w = f2bf(e4.w);
    ((ushort4*)ea_sb)[p] = eb;
}

// ---------------------------------------------------------------------------
// edge message MFMA kernel. 128 sorted edges/chunk, wave-private slabs.
// K-loop covers K=128 (h_src|h_dst); edge-attr via register-built A-frag MFMA
// against Wb1 cols 128..159 (zero past 132 -> garbage annihilated).
// ---------------------------------------------------------------------------
__global__ __launch_bounds__(256, 3) void edge_msg_mfma(
    const ushort* __restrict__ hb, const int* __restrict__ src_s,
    const int* __restrict__ dst_s, const ushort* __restrict__ ea_sb,
    const ushort* __restrict__ Wb1l, const ushort* __restrict__ Wb2l,
    const float* __restrict__ b1, const float* __restrict__ b2,
    float* __restrict__ agg, int E, int nchunks) {
    __shared__ char lds[4 * SLABSZ + 4 * HIDSZ];  // 53248 B
    int tid = threadIdx.x;
    int w = tid >> 6, lane = tid & 63;
    int quad = lane >> 4, nrow = lane & 15;
    char* slab = lds + w * SLABSZ;
    char* hidb = lds + 4 * SLABSZ + w * HIDSZ;

    // preload weight B-fragments + biases (per-dispatch constants)
    bf16x8 wf1[4][4], wfea[4], wf2[4][2];
    float b1v[4], b2v[4];
#pragma unroll
    for (int nt = 0; nt < 4; nt++) {
        int n = nt * 16 + nrow;
#pragma unroll
        for (int ks = 0; ks < 4; ks++)
            wf1[nt][ks] = *(const bf16x8*)(Wb1l + n * 160 + ks * 32 + quad * 8);
        wfea[nt] = *(const bf16x8*)(Wb1l + n * 160 + 128 + quad * 8);
#pragma unroll
        for (int ks = 0; ks < 2; ks++)
            wf2[nt][ks] = *(const bf16x8*)(Wb2l + n * 64 + ks * 32 + quad * 8);
        b1v[nt] = b1[n];
        b2v[nt] = b2[n];
    }

    for (int chunk = blockIdx.x; chunk < nchunks; chunk += gridDim.x) {
        int ebase = chunk * CHUNK;
        // ---- stage x rows (2 threads per edge, h_src | h_dst only) ----
        {
            int el = tid >> 1, half = tid & 1;
            int r = el & 31;
            int ec = min(ebase + el, E - 1);
            int node = half ? dst_s[ec] : src_s[ec];
            const float4* hrow = (const float4*)(hb + (size_t)node * 64);
            float4* xw = (float4*)(slab + r * XSTRIDE + half * 128);
#pragma unroll
            for (int i = 0; i < 8; i++) xw[i] = hrow[i];
        }
        // ---- edge-attr A-frags (quad 0 lanes only; rest zero) ----
        bf16x8 ea0 = {0, 0, 0, 0, 0, 0, 0, 0};
        bf16x8 ea1 = {0, 0, 0, 0, 0, 0, 0, 0};
        if (quad == 0) {
            int ec0 = min(ebase + w * 32 + nrow, E - 1);
            int ec1 = min(ebase + w * 32 + 16 + nrow, E - 1);
            *(uint2*)&ea0 = *(const uint2*)(ea_sb + (size_t)ec0 * 4);
            *(uint2*)&ea1 = *(const uint2*)(ea_sb + (size_t)ec1 * 4);
        }
        // ---- layer 1: [32 x 132] @ [132 x 64] ----
        f32x4 acc1[2][4];
#pragma unroll
        for (int mt = 0; mt < 2; mt++)
#pragma unroll
            for (int nt = 0; nt < 4; nt++) {
                f32x4 v;
                v[0] = v[1] = v[2] = v[3] = b1v[nt];
                acc1[mt][nt] = v;
            }
#pragma unroll
        for (int ks = 0; ks < 4; ks++) {
            bf16x8 a0 = *(const bf16x8*)(slab + nrow * XSTRIDE + ks * 64 + quad * 16);
            bf16x8 a1 = *(const bf16x8*)(slab + (16 + nrow) * XSTRIDE + ks * 64 + quad * 16);
#pragma unroll
            for (int nt = 0; nt < 4; nt++) {
                acc1[0][nt] = MFMA16(a0, wf1[nt][ks], acc1[0][nt]);
                acc1[1][nt] = MFMA16(a1, wf1[nt][ks], acc1[1][nt]);
            }
        }
#pragma unroll
        for (int nt = 0; nt < 4; nt++) {
            acc1[0][nt] = MFMA16(ea0, wfea[nt], acc1[0][nt]);
            acc1[1][nt] = MFMA16(ea1, wfea[nt], acc1[1][nt]);
        }
        // ---- SiLU -> hid (bf16, A-layout rows) ----
#pragma unroll
        for (int mt = 0; mt < 2; mt++)
#pragma unroll
            for (int nt = 0; nt < 4; nt++)
#pragma unroll
                for (int rg = 0; rg < 4; rg++) {
                    float v = acc1[mt][nt][rg];
                    v = v * fast_sig(v);
                    int rm = mt * 16 + quad * 4 + rg;
                    *(ushort*)(hidb + rm * HSTRIDE + (nt * 16 + nrow) * 2) = f2bf(v);
                }
        // ---- layer 2: [32 x 64] @ [64 x 64] ----
        f32x4 acc2[2][4];
#pragma unroll
        for (int mt = 0; mt < 2; mt++)
#pragma unroll
            for (int nt = 0; nt < 4; nt++) {
                f32x4 v;
                v[0] = v[1] = v[2] = v[3] = b2v[nt];
                acc2[mt][nt] = v;
            }
#pragma unroll
        for (int ks = 0; ks < 2; ks++) {
            bf16x8 a0 = *(const bf16x8*)(hidb + nrow * HSTRIDE + ks * 64 + quad * 16);
            bf16x8 a1 = *(const bf16x8*)(hidb + (16 + nrow) * HSTRIDE + ks * 64 + quad * 16);
#pragma unroll
            for (int nt = 0; nt < 4; nt++) {
                acc2[0][nt] = MFMA16(a0, wf2[nt][ks], acc2[0][nt]);
                acc2[1][nt] = MFMA16(a1, wf2[nt][ks], acc2[1][nt]);
            }
        }
        // ---- m -> slab (f32, aliases x region; wave-private, no barrier) ----
#pragma unroll
        for (int mt = 0; mt < 2; mt++)
#pragma unroll
            for (int nt = 0; nt < 4; nt++)
#pragma unroll
                for (int rg = 0; rg < 4; rg++) {
                    int rm = mt * 16 + quad * 4 + rg;
                    *(float*)(slab + rm * MSTRIDE + (nt * 16 + nrow) * 4) = acc2[mt][nt][rg];
                }
        // ---- segmented aggregation over this wave's 32 sorted edges ----
        {
            int e32 = ebase + w * 32;
            int dmy = dst_s[min(e32 + (lane & 31), E - 1)];
            int limit = min(32, E - e32);
            int nx = __shfl_down(dmy, 1);
            bool tl = ((lane & 31) == 31) || (dmy != nx);
            unsigned long long tm = __ballot(tl);
            float run = 0.f;
#pragma unroll
            for (int i = 0; i < 32; i++) {
                if (i < limit) {
                    run += *(const float*)(slab + i * MSTRIDE + lane * 4);
                    if (((tm >> i) & 1ull) || (i + 1 == limit)) {
                        int di = __shfl(dmy, i);
                        unsafeAtomicAdd(&agg[(size_t)di * 64 + lane], run);
                        run = 0.f;
                    }
                }
            }
        }
    }
}

// ---------------------------------------------------------------------------
// head MFMA kernel (original edge order; ea is fp32).
// ---------------------------------------------------------------------------
__global__ __launch_bounds__(256, 3) void head_mfma(
    const ushort* __restrict__ hb, const int* __restrict__ src,
    const int* __restrict__ dst, const float* __restrict__ ea,
    const ushort* __restrict__ Wh1, const ushort* __restrict__ Wh2b,
    const float* __restrict__ hb1, const float* __restrict__ hb2p,
    float* __restrict__ out, int E, int nchunks) {
    __shared__ char lds[4 * SLABSZ + 4 * HIDSZ];
    int tid = threadIdx.x;
    int w = tid >> 6, lane = tid & 63;
    int quad = lane >> 4, nrow = lane & 15;
    char* slab = lds + w * SLABSZ;
    char* hidb = lds + 4 * SLABSZ + w * HIDSZ;

    bf16x8 wf1[4][4], wfea[4], wh2[2];
    float b1v[4];
#pragma unroll
    for (int nt = 0; nt < 4; nt++) {
        int n = nt * 16 + nrow;
#pragma unroll
        for (int ks = 0; ks < 4; ks++)
            wf1[nt][ks] = *(const bf16x8*)(Wh1 + n * 160 + ks * 32 + quad * 8);
        wfea[nt] = *(const bf16x8*)(Wh1 + n * 160 + 128 + quad * 8);
        b1v[nt] = hb1[n];
    }
#pragma unroll
    for (int ks = 0; ks < 2; ks++)
        wh2[ks] = *(const bf16x8*)(Wh2b + nrow * 64 + ks * 32 + quad * 8);
    float hb2 = hb2p[0];

    for (int chunk = blockIdx.x; chunk < nchunks; chunk += gridDim.x) {
        int ebase = chunk * CHUNK;
        {
            int el = tid >> 1, half = tid & 1;
            int r = el & 31;
            int ec = min(ebase + el, E - 1);
            int node = half ? dst[ec] : src[ec];
            const float4* hrow = (const float4*)(hb + (size_t)node * 64);
            float4* xw = (float4*)(slab + r * XSTRIDE + half * 128);
#pragma unroll
            for (int i = 0; i < 8; i++) xw[i] = hrow[i];
        }
        bf16x8 ea0 = {0, 0, 0, 0, 0, 0, 0, 0};
        bf16x8 ea1 = {0, 0, 0, 0, 0, 0, 0, 0};
        if (quad == 0) {
            int ec0 = min(ebase + w * 32 + nrow, E - 1);
            int ec1 = min(ebase + w * 32 + 16 + nrow, E - 1);
            float4 e0 = ((const float4*)ea)[ec0];
            float4 e1 = ((const float4*)ea)[ec1];
            ushort4 u0, u1;
            u0.x = f2bf(e0.x); u0.y = f2bf(e0.y); u0.z = f2bf(e0.z); u0.w = f2bf(e0.w);
            u1.x = f2bf(e1.x); u1.y = f2bf(e1.y); u1.z = f2bf(e1.z); u1.w = f2bf(e1.w);
            *(ushort4*)&ea0 = u0;
            *(ushort4*)&ea1 = u1;
        }
        f32x4 acc1[2][4];
#pragma unroll
        for (int mt = 0; mt < 2; mt++)
#pragma unroll
            for (int nt = 0; nt < 4; nt++) {
                f32x4 v;
                v[0] = v[1] = v[2] = v[3] = b1v[nt];
                acc1[mt][nt] = v;
            }
#pragma unroll
        for (int ks = 0; ks < 4; ks++) {
            bf16x8 a0 = *(const bf16x8*)(slab + nrow * XSTRIDE + ks * 64 + quad * 16);
            bf16x8 a1 = *(const bf16x8*)(slab + (16 + nrow) * XSTRIDE + ks * 64 + quad * 16);
#pragma unroll
            for (int nt = 0; nt < 4; nt++) {
                acc1[0][nt] = MFMA16(a0, wf1[nt][ks], acc1[0][nt]);
                acc1[1][nt] = MFMA16(a1, wf1[nt][ks], acc1[1][nt]);
            }
        }
#pragma unroll
        for (int nt = 0; nt < 4; nt++) {
            acc1[0][nt] = MFMA16(ea0, wfea[nt], acc1[0][nt]);
            acc1[1][nt] = MFMA16(ea1, wfea[nt], acc1[1][nt]);
        }
#pragma unroll
        for (int mt = 0; mt < 2; mt++)
#pragma unroll
            for (int nt = 0; nt < 4; nt++)
#pragma unroll
                for (int rg = 0; rg < 4; rg++) {
                    float v = acc1[mt][nt][rg];
                    v = v * fast_sig(v);
                    int rm = mt * 16 + quad * 4 + rg;
                    *(ushort*)(hidb + rm * HSTRIDE + (nt * 16 + nrow) * 2) = f2bf(v);
                }
        f32x4 acc3[2];
#pragma unroll
        for (int mt = 0; mt < 2; mt++) {
            f32x4 v;
            v[0] = v[1] = v[2] = v[3] = 0.f;
            acc3[mt] = v;
        }
#pragma unroll
        for (int ks = 0; ks < 2; ks++) {
            bf16x8 a0 = *(const bf16x8*)(hidb + nrow * HSTRIDE + ks * 64 + quad * 16);
            bf16x8 a1 = *(const bf16x8*)(hidb + (16 + nrow) * HSTRIDE + ks * 64 + quad * 16);
            acc3[0] = MFMA16(a0, wh2[ks], acc3[0]);
            acc3[1] = MFMA16(a1, wh2[ks], acc3[1]);
        }
        if (nrow == 0) {
#pragma unroll
            for (int mt = 0; mt < 2; mt++)
#pragma unroll
                for (int rg = 0; rg < 4; rg++) {
                    int e = ebase + w * 32 + mt * 16 + quad * 4 + rg;
                    if (e < E) out[e] = fast_sig(acc3[mt][rg] + hb2);
                }
        }
    }
}

// ---------------------------------------------------------------------------
// GRU MFMA kernel + self-zeroing of agg for the next layer.
// ---------------------------------------------------------------------------
__device__ __forceinline__ bf16x8 aggfrag(const float* __restrict__ row, int off) {
    float4 f0 = *(const float4*)(row + off);
    float4 f1 = *(const float4*)(row + off + 4);
    bf16x8 r;
    r[0] = (short)f2bf(f0.x); r[1] = (short)f2bf(f0.y);
    r[2] = (short)f2bf(f0.z); r[3] = (short)f2bf(f0.w);
    r[4] = (short)f2bf(f1.x); r[5] = (short)f2bf(f1.y);
    r[6] = (short)f2bf(f1.z); r[7] = (short)f2bf(f1.w);
    return r;
}

__global__ __launch_bounds__(256) void gru_mfma(
    float* __restrict__ h, ushort* __restrict__ hb, float* __restrict__ agg,
    const ushort* __restrict__ Wrzg, const ushort* __restrict__ Wnig,
    const ushort* __restrict__ Wnhg,
    const float* __restrict__ bih, const float* __restrict__ bhh, int N) {
    __shared__ char lds[128 * WRZST + 2 * 64 * WNST];  // 51200 B
    int tid = threadIdx.x, w = tid >> 6, lane = tid & 63;
    int quad = lane >> 4, nrow = lane & 15;
    char* wrz = lds;
    char* wni = lds + 128 * WRZST;
    char* wnh = wni + 64 * WNST;

    {
        int r = tid >> 1, half = tid & 1;
        const uint4* g = (const uint4*)(Wrzg + r * 128 + half * 64);
        uint4* d = (uint4*)(wrz + r * WRZST + half * 128);
#pragma unroll
        for (int i = 0; i < 8; i++) d[i] = g[i];
        if (tid < 128) {
            const uint4* g2 = (const uint4*)(Wnig + (tid >> 1) * 64 + (tid & 1) * 32);
            uint4* d2 = (uint4*)(wni + (tid >> 1) * WNST + (tid & 1) * 64);
#pragma unroll
            for (int i = 0; i < 4; i++) d2[i] = g2[i];
        } else {
            int t2 = tid - 128;
            const uint4* g2 = (const uint4*)(Wnhg + (t2 >> 1) * 64 + (t2 & 1) * 32);
            uint4* d2 = (uint4*)(wnh + (t2 >> 1) * WNST + (t2 & 1) * 64);
#pragma unroll
            for (int i = 0; i < 4; i++) d2[i] = g2[i];
        }
    }
    __syncthreads();

    int nb0 = blockIdx.x * 128 + w * 32;
    if (nb0 >= N) return;

    float brz[8], bi[4], bhv[4];
#pragma unroll
    for (int nt = 0; nt < 8; nt++) brz[nt] = bih[nt * 16 + nrow] + bhh[nt * 16 + nrow];
#pragma unroll
    for (int nt = 0; nt < 4; nt++) {
        bi[nt] = bih[128 + nt * 16 + nrow];
        bhv[nt] = bhh[128 + nt * 16 + nrow];
    }

    int n0 = min(nb0 + nrow, N - 1);
    int n1 = min(nb0 + 16 + nrow, N - 1);
    const float* ag0 = agg + (size_t)n0 * 64;
    const float* ag1 = agg + (size_t)n1 * 64;
    const ushort* hb0 = hb + (size_t)n0 * 64;
    const ushort* hb1 = hb + (size_t)n1 * 64;

    f32x4 accrz[2][8], acci[2][4], acch[2][4];
#pragma unroll
    for (int nt = 0; nt < 8; nt++) {
        f32x4 v; v[0] = v[1] = v[2] = v[3] = brz[nt];
        accrz[0][nt] = v; accrz[1][nt] = v;
    }
#pragma unroll
    for (int nt = 0; nt < 4; nt++) {
        f32x4 vi; vi[0] = vi[1] = vi[2] = vi[3] = bi[nt];
        acci[0][nt] = vi; acci[1][nt] = vi;
        f32x4 vh; vh[0] = vh[1] = vh[2] = vh[3] = bhv[nt];
        acch[0][nt] = vh; acch[1][nt] = vh;
    }

#pragma unroll
    for (int ks = 0; ks < 4; ks++) {
        bf16x8 a0, a1;
        if (ks < 2) {
            a0 = aggfrag(ag0, ks * 32 + quad * 8);
            a1 = aggfrag(ag1, ks * 32 + quad * 8);
        } else {
            a0 = *(const bf16x8*)(hb0 + (ks - 2) * 32 + quad * 8);
            a1 = *(const bf16x8*)(hb1 + (ks - 2) * 32 + quad * 8);
        }
#pragma unroll
        for (int nt = 0; nt < 8; nt++) {
            bf16x8 b = *(const bf16x8*)(wrz + (nt * 16 + nrow) * WRZST + ks * 64 + quad * 16);
            accrz[0][nt] = MFMA16(a0, b, accrz[0][nt]);
            accrz[1][nt] = MFMA16(a1, b, accrz[1][nt]);
        }
        if (ks < 2) {
#pragma unroll
            for (int nt = 0; nt < 4; nt++) {
                bf16x8 b = *(const bf16x8*)(wni + (nt * 16 + nrow) * WNST + ks * 64 + quad * 16);
                acci[0][nt] = MFMA16(a0, b, acci[0][nt]);
                acci[1][nt] = MFMA16(a1, b, acci[1][nt]);
            }
        } else {
#pragma unroll
            for (int nt = 0; nt < 4; nt++) {
                bf16x8 b = *(const bf16x8*)(wnh + (nt * 16 + nrow) * WNST + (ks - 2) * 64 + quad * 16);
                acch[0][nt] = MFMA16(a0, b, acch[0][nt]);
                acch[1][nt] = MFMA16(a1, b, acch[1][nt]);
            }
        }
    }

    // gates + h update (C-layout elementwise)
#pragma unroll
    for (int mt = 0; mt < 2; mt++)
#pragma unroll
        for (int nt = 0; nt < 4; nt++)
#pragma unroll
            for (int rg = 0; rg < 4; rg++) {
                int node = nb0 + mt * 16 + quad * 4 + rg;
                if (node < N) {
                    int col = nt * 16 + nrow;
                    float r = fast_sig(accrz[mt][nt][rg]);
                    float z = fast_sig(accrz[mt][nt + 4][rg]);
                    float nn = fast_tanh(acci[mt][nt][rg] + r * acch[mt][nt][rg]);
                    size_t idx = (size_t)node * 64 + col;
                    float ho = h[idx];
                    float hnew = (1.f - z) * nn + z * ho;
                    h[idx] = hnew;
                    hb[idx] = f2bf(hnew);
                }
            }

    // zero this wave's OWN agg rows for the next layer (guarded: only rows
    // this wave exclusively owns, so no cross-wave read/write race)
    {
        float4 z4 = {0.f, 0.f, 0.f, 0.f};
        if (nb0 + nrow < N) {
            float* a = agg + (size_t)(nb0 + nrow) * 64;
            *(float4*)(a + quad * 8) = z4;
            *(float4*)(a + quad * 8 + 4) = z4;
            *(float4*)(a + 32 + quad * 8) = z4;
            *(float4*)(a + 32 + quad * 8 + 4) = z4;
        }
        if (nb0 + 16 + nrow < N) {
            float* a = agg + (size_t)(nb0 + 16 + nrow) * 64;
            *(float4*)(a + quad * 8) = z4;
            *(float4*)(a + quad * 8 + 4) = z4;
            *(float4*)(a + 32 + quad * 8) = z4;
            *(float4*)(a + 32 + quad * 8 + 4) = z4;
        }
    }
}

extern "C" void kernel_launch(void* const* d_in, const int* in_sizes, int n_in,
                              void* d_out, int out_size, void* d_ws, size_t ws_size,
                              hipStream_t stream) {
    const int* edge_index = (const int*)d_in[0];
    int E = in_sizes[0] / 2;
    const int* src = edge_index;
    const int* dst = edge_index + E;
    const int* kinds = (const int*)d_in[1];
    int N = in_sizes[1];
    const float* edge_attr = (const float*)d_in[2];
    const float* emb = (const float*)d_in[3];
    const float* msg_w1 = (const float*)d_in[4];
    const float* msg_b1 = (const float*)d_in[5];
    const float* msg_w2 = (const float*)d_in[6];
    const float* msg_b2 = (const float*)d_in[7];
    const float* gru_wih = (const float*)d_in[8];
    const float* gru_whh = (const float*)d_in[9];
    const float* gru_bih = (const float*)d_in[10];
    const float* gru_bhh = (const float*)d_in[11];
    const float* head_w1 = (const float*)d_in[12];
    const float* head_b1 = (const float*)d_in[13];
    const float* head_w2 = (const float*)d_in[14];
    const float* head_b2 = (const float*)d_in[15];
    float* out = (float*)d_out;

    // workspace carve-up
    char* p = (char*)d_ws;
    float* h = (float*)p;        p += (size_t)N * 64 * 4;
    float* agg = (float*)p;      p += (size_t)N * 64 * 4;
    int* deg = (int*)p;          p += (size_t)N * 4;
    int* cursor = (int*)p;       p += (size_t)N * 4;
    int* src_s = (int*)p;        p += (size_t)E * 4;
    int* dst_s = (int*)p;        p += (size_t)E * 4;
    ushort* hb = (ushort*)p;     p += (size_t)N * 64 * 2;
    ushort* Wb1 = (ushort*)p;    p += 30720 * 2;
    ushort* Wb2 = (ushort*)p;    p += 12288 * 2;
    ushort* Wh1 = (ushort*)p;    p += 10240 * 2;
    ushort* Wh2b = (ushort*)p;   p += 1024 * 2;
    ushort* Wrz = (ushort*)p;    p += 49152 * 2;
    ushort* Wni = (ushort*)p;    p += 12288 * 2;
    ushort* Wnh = (ushort*)p;    p += 12288 * 2;
    ushort* ea_sb = (ushort*)p;  p += (size_t)E * 4 * 2;

    int nchunks = (E + CHUNK - 1) / CHUNK;

    prep_kernel<<<500, 256, 0, stream>>>(msg_w1, msg_w2, gru_wih, gru_whh, head_w1,
                                         head_w2, Wb1, Wb2, Wh1, Wh2b, Wrz, Wni, Wnh);
    embed_kernel<<<(N * 64 + 255) / 256, 256, 0, stream>>>(h, hb, emb, kinds, N);

    hipMemsetAsync(deg, 0, (size_t)N * sizeof(int), stream);
    hipMemsetAsync(agg, 0, (size_t)N * 64 * sizeof(float), stream);
    hist_kernel<<<(E + 255) / 256, 256, 0, stream>>>(dst, deg, E);
    scan_kernel<<<1, 1024, 0, stream>>>(deg, cursor, N);
    scatter_kernel<<<(E + 255) / 256, 256, 0, stream>>>(src, dst, edge_attr, cursor,
                                                        src_s, dst_s, ea_sb, E);

    for (int l = 0; l < 3; l++) {
        edge_msg_mfma<<<2048, 256, 0, stream>>>(
            hb, src_s, dst_s, ea_sb,
            Wb1 + l * 10240, Wb2 + l * 4096,
            msg_b1 + l * 64, msg_b2 + l * 64, agg, E, nchunks);
        gru_mfma<<<(N + 127) / 128, 256, 0, stream>>>(
            h, hb, agg, Wrz + l * 16384, Wni + l * 4096, Wnh + l * 4096,
            gru_bih + l * 192, gru_bhh + l * 192, N);
    }
    head_mfma<<<2048, 256, 0, stream>>>(hb, src, dst, edge_attr, Wh1, Wh2b,
                                        head_b1, head_b2, out, E, nchunks);
}

// Round 6
// 755.442 us; speedup vs baseline: 1.1117x; 1.1117x over previous
//
#include <hip/hip_runtime.h>
#include <hip/hip_bf16.h>

// ---------------------------------------------------------------------------
// HazardGNN round 6: revert the launch_bounds(256,3) min-waves bound (it made
// the allocator spill the register-resident weight fragments: VGPR 128->84,
// FETCH 35->223MB, WRITE 18->135MB = scratch traffic). Keep the r5 LDS shrink
// (53248 B -> 3 blocks/CU naturally at VGPR=128). Grid 768 persistent.
// ---------------------------------------------------------------------------

typedef __attribute__((ext_vector_type(8))) short bf16x8;
typedef __attribute__((ext_vector_type(4))) float f32x4;
#define MFMA16(a, b, c) __builtin_amdgcn_mfma_f32_16x16x32_bf16(a, b, c, 0, 0, 0)

#define CHUNK 128
#define XSTRIDE 272   // bytes per x row: 128 (h_src) + 128 (h_dst) + 16 pad
#define MSTRIDE 264   // bytes per m row: 66 f32 (aliases x slab)
#define HSTRIDE 144   // bytes per hid row: 72 bf16
#define SLABSZ 8704   // 32 * XSTRIDE
#define HIDSZ  4608   // 32 * HSTRIDE
// edge/head LDS: 4*8704 + 4*4608 = 53248 B -> 3 blocks/CU (LDS-bound)

// GRU LDS strides (+8 bf16 pad to break power-of-2 banking)
#define WRZST 264     // 128 bf16 + 4 pad
#define WNST  136     // 64 bf16 + 4 pad

__device__ __forceinline__ float fast_sig(float x) { return 1.f / (1.f + __expf(-x)); }
__device__ __forceinline__ float fast_tanh(float x) {
    float ax = fabsf(x);
    float t = __expf(-2.f * ax);
    return copysignf((1.f - t) / (1.f + t), x);
}
__device__ __forceinline__ ushort f2bf(float f) {  // RNE fp32->bf16
    unsigned u = __float_as_uint(f);
    unsigned r = u + 0x7FFF + ((u >> 16) & 1);
    return (ushort)(r >> 16);
}

// ---------------------------------------------------------------------------
// prep: bf16 weight images (row-major [out][K], K padded to 160 with zeros)
// + stacked GRU weights.
// ---------------------------------------------------------------------------
__global__ void prep_kernel(const float* __restrict__ msg_w1,
                            const float* __restrict__ msg_w2,
                            const float* __restrict__ gru_wih,
                            const float* __restrict__ gru_whh,
                            const float* __restrict__ head_w1,
                            const float* __restrict__ head_w2,
                            ushort* __restrict__ Wb1, ushort* __restrict__ Wb2,
                            ushort* __restrict__ Wh1, ushort* __restrict__ Wh2b,
                            ushort* __restrict__ Wrz, ushort* __restrict__ Wni,
                            ushort* __restrict__ Wnh) {
    int t = blockIdx.x * 256 + threadIdx.x;
    if (t < 30720) {  // Wb1[l][j][k<160]
        int l = t / 10240, r = t % 10240, j = r / 160, k = r % 160;
        Wb1[t] = (k < 132) ? f2bf(msg_w1[l * 8448 + j * 132 + k]) : 0;
        return;
    }
    t -= 30720;
    if (t < 12288) {  // Wb2[l][j][k<64]
        Wb2[t] = f2bf(msg_w2[t]);
        return;
    }
    t -= 12288;
    if (t < 10240) {  // Wh1[j][k<160]
        int j = t / 160, k = t % 160;
        Wh1[t] = (k < 132) ? f2bf(head_w1[j * 132 + k]) : 0;
        return;
    }
    t -= 10240;
    if (t < 1024) {  // Wh2b[16][64]: row 0 = head_w2, rows 1..15 zero
        int j = t >> 6, k = t & 63;
        Wh2b[t] = (j == 0) ? f2bf(head_w2[k]) : 0;
        return;
    }
    t -= 1024;
    if (t < 49152) {  // Wrz[l][n][k]: k<64 wih, k>=64 whh
        int l = t / 16384, r = t % 16384, n = r >> 7, k = r & 127;
        float v = (k < 64) ? gru_wih[l * 12288 + n * 64 + k]
                           : gru_whh[l * 12288 + n * 64 + (k - 64)];
        Wrz[t] = f2bf(v);
        return;
    }
    t -= 49152;
    if (t < 12288) {  // Wni[l][j][k]
        int l = t / 4096, r = t % 4096, j = r >> 6, k = r & 63;
        Wni[t] = f2bf(gru_wih[l * 12288 + (128 + j) * 64 + k]);
        return;
    }
    t -= 12288;
    if (t < 12288) {  // Wnh[l][j][k]
        int l = t / 4096, r = t % 4096, j = r >> 6, k = r & 63;
        Wnh[t] = f2bf(gru_whh[l * 12288 + (128 + j) * 64 + k]);
    }
}

// h (fp32) + hb (bf16 mirror) from embedding
__global__ void embed_kernel(float* __restrict__ h, ushort* __restrict__ hb,
                             const float* __restrict__ emb,
                             const int* __restrict__ kinds, int N) {
    int t = blockIdx.x * 256 + threadIdx.x;
    if (t >= N * 64) return;
    int node = t >> 6, d = t & 63;
    float v = emb[kinds[node] * 64 + d];
    h[t] = v;
    hb[t] = f2bf(v);
}

// -------------------- counting sort by dst --------------------
__global__ void hist_kernel(const int* __restrict__ dst, int* __restrict__ deg, int E) {
    int e = blockIdx.x * 256 + threadIdx.x;
    if (e < E) atomicAdd(&deg[dst[e]], 1);
}

__global__ void scan_kernel(const int* __restrict__ deg, int* __restrict__ cursor, int N) {
    __shared__ int sums[1024];
    int tid = threadIdx.x;
    int chunk = (N + 1023) >> 10;
    int lo = tid * chunk, hi = min(lo + chunk, N);
    int s = 0;
    for (int i = lo; i < hi; i++) s += deg[i];
    sums[tid] = s;
    __syncthreads();
    for (int off = 1; off < 1024; off <<= 1) {
        int v = (tid >= off) ? sums[tid - off] : 0;
        __syncthreads();
        sums[tid] += v;
        __syncthreads();
    }
    int run = (tid > 0) ? sums[tid - 1] : 0;
    for (int i = lo; i < hi; i++) {
        cursor[i] = run;
        run += deg[i];
    }
}

__global__ void scatter_kernel(const int* __restrict__ src, const int* __restrict__ dst,
                               const float* __restrict__ ea, int* __restrict__ cursor,
                               int* __restrict__ src_s, int* __restrict__ dst_s,
                               ushort* __restrict__ ea_sb, int E) {
    int e = blockIdx.x * 256 + threadIdx.x;
    if (e >= E) return;
    int d = dst[e];
    int p = atomicAdd(&cursor[d], 1);
    src_s[p] = src[e];
    dst_s[p] = d;
    float4 e4 = ((const float4*)ea)[e];
    ushort4 eb;
    eb.x = f2bf(e4.x); eb.y = f2bf(e4.y); eb.z = f2bf(e4.z); eb.w = f2bf(e4.w);
    ((ushort4*)ea_sb)[p] = eb;
}

// ---------------------------------------------------------------------------
// edge message MFMA kernel. 128 sorted edges/chunk, wave-private slabs.
// K-loop covers K=128 (h_src|h_dst); edge-attr via register-built A-frag MFMA
// against Wb1 cols 128..159 (zero past 132 -> garbage annihilated).
// NOTE: plain __launch_bounds__(256) — an explicit min-waves bound makes the
// allocator spill the ~112 VGPRs of weight fragments (measured r5: VGPR 84,
// +305 MB/dispatch scratch traffic, 1.6x slower).
// ---------------------------------------------------------------------------
__global__ __launch_bounds__(256) void edge_msg_mfma(
    const ushort* __restrict__ hb, const int* __restrict__ src_s,
    const int* __restrict__ dst_s, const ushort* __restrict__ ea_sb,
    const ushort* __restrict__ Wb1l, const ushort* __restrict__ Wb2l,
    const float* __restrict__ b1, const float* __restrict__ b2,
    float* __restrict__ agg, int E, int nchunks) {
    __shared__ char lds[4 * SLABSZ + 4 * HIDSZ];  // 53248 B
    int tid = threadIdx.x;
    int w = tid >> 6, lane = tid & 63;
    int quad = lane >> 4, nrow = lane & 15;
    char* slab = lds + w * SLABSZ;
    char* hidb = lds + 4 * SLABSZ + w * HIDSZ;

    // preload weight B-fragments + biases (per-dispatch constants)
    bf16x8 wf1[4][4], wfea[4], wf2[4][2];
    float b1v[4], b2v[4];
#pragma unroll
    for (int nt = 0; nt < 4; nt++) {
        int n = nt * 16 + nrow;
#pragma unroll
        for (int ks = 0; ks < 4; ks++)
            wf1[nt][ks] = *(const bf16x8*)(Wb1l + n * 160 + ks * 32 + quad * 8);
        wfea[nt] = *(const bf16x8*)(Wb1l + n * 160 + 128 + quad * 8);
#pragma unroll
        for (int ks = 0; ks < 2; ks++)
            wf2[nt][ks] = *(const bf16x8*)(Wb2l + n * 64 + ks * 32 + quad * 8);
        b1v[nt] = b1[n];
        b2v[nt] = b2[n];
    }

    for (int chunk = blockIdx.x; chunk < nchunks; chunk += gridDim.x) {
        int ebase = chunk * CHUNK;
        // ---- stage x rows (2 threads per edge, h_src | h_dst only) ----
        {
            int el = tid >> 1, half = tid & 1;
            int r = el & 31;
            int ec = min(ebase + el, E - 1);
            int node = half ? dst_s[ec] : src_s[ec];
            const float4* hrow = (const float4*)(hb + (size_t)node * 64);
            float4* xw = (float4*)(slab + r * XSTRIDE + half * 128);
#pragma unroll
            for (int i = 0; i < 8; i++) xw[i] = hrow[i];
        }
        // ---- edge-attr A-frags (quad 0 lanes only; rest zero) ----
        bf16x8 ea0 = {0, 0, 0, 0, 0, 0, 0, 0};
        bf16x8 ea1 = {0, 0, 0, 0, 0, 0, 0, 0};
        if (quad == 0) {
            int ec0 = min(ebase + w * 32 + nrow, E - 1);
            int ec1 = min(ebase + w * 32 + 16 + nrow, E - 1);
            *(uint2*)&ea0 = *(const uint2*)(ea_sb + (size_t)ec0 * 4);
            *(uint2*)&ea1 = *(const uint2*)(ea_sb + (size_t)ec1 * 4);
        }
        // ---- layer 1: [32 x 132] @ [132 x 64] ----
        f32x4 acc1[2][4];
#pragma unroll
        for (int mt = 0; mt < 2; mt++)
#pragma unroll
            for (int nt = 0; nt < 4; nt++) {
                f32x4 v;
                v[0] = v[1] = v[2] = v[3] = b1v[nt];
                acc1[mt][nt] = v;
            }
#pragma unroll
        for (int ks = 0; ks < 4; ks++) {
            bf16x8 a0 = *(const bf16x8*)(slab + nrow * XSTRIDE + ks * 64 + quad * 16);
            bf16x8 a1 = *(const bf16x8*)(slab + (16 + nrow) * XSTRIDE + ks * 64 + quad * 16);
#pragma unroll
            for (int nt = 0; nt < 4; nt++) {
                acc1[0][nt] = MFMA16(a0, wf1[nt][ks], acc1[0][nt]);
                acc1[1][nt] = MFMA16(a1, wf1[nt][ks], acc1[1][nt]);
            }
        }
#pragma unroll
        for (int nt = 0; nt < 4; nt++) {
            acc1[0][nt] = MFMA16(ea0, wfea[nt], acc1[0][nt]);
            acc1[1][nt] = MFMA16(ea1, wfea[nt], acc1[1][nt]);
        }
        // ---- SiLU -> hid (bf16, A-layout rows) ----
#pragma unroll
        for (int mt = 0; mt < 2; mt++)
#pragma unroll
            for (int nt = 0; nt < 4; nt++)
#pragma unroll
                for (int rg = 0; rg < 4; rg++) {
                    float v = acc1[mt][nt][rg];
                    v = v * fast_sig(v);
                    int rm = mt * 16 + quad * 4 + rg;
                    *(ushort*)(hidb + rm * HSTRIDE + (nt * 16 + nrow) * 2) = f2bf(v);
                }
        // ---- layer 2: [32 x 64] @ [64 x 64] ----
        f32x4 acc2[2][4];
#pragma unroll
        for (int mt = 0; mt < 2; mt++)
#pragma unroll
            for (int nt = 0; nt < 4; nt++) {
                f32x4 v;
                v[0] = v[1] = v[2] = v[3] = b2v[nt];
                acc2[mt][nt] = v;
            }
#pragma unroll
        for (int ks = 0; ks < 2; ks++) {
            bf16x8 a0 = *(const bf16x8*)(hidb + nrow * HSTRIDE + ks * 64 + quad * 16);
            bf16x8 a1 = *(const bf16x8*)(hidb + (16 + nrow) * HSTRIDE + ks * 64 + quad * 16);
#pragma unroll
            for (int nt = 0; nt < 4; nt++) {
                acc2[0][nt] = MFMA16(a0, wf2[nt][ks], acc2[0][nt]);
                acc2[1][nt] = MFMA16(a1, wf2[nt][ks], acc2[1][nt]);
            }
        }
        // ---- m -> slab (f32, aliases x region; wave-private, no barrier) ----
#pragma unroll
        for (int mt = 0; mt < 2; mt++)
#pragma unroll
            for (int nt = 0; nt < 4; nt++)
#pragma unroll
                for (int rg = 0; rg < 4; rg++) {
                    int rm = mt * 16 + quad * 4 + rg;
                    *(float*)(slab + rm * MSTRIDE + (nt * 16 + nrow) * 4) = acc2[mt][nt][rg];
                }
        // ---- segmented aggregation over this wave's 32 sorted edges ----
        {
            int e32 = ebase + w * 32;
            int dmy = dst_s[min(e32 + (lane & 31), E - 1)];
            int limit = min(32, E - e32);
            int nx = __shfl_down(dmy, 1);
            bool tl = ((lane & 31) == 31) || (dmy != nx);
            unsigned long long tm = __ballot(tl);
            float run = 0.f;
#pragma unroll
            for (int i = 0; i < 32; i++) {
                if (i < limit) {
                    run += *(const float*)(slab + i * MSTRIDE + lane * 4);
                    if (((tm >> i) & 1ull) || (i + 1 == limit)) {
                        int di = __shfl(dmy, i);
                        unsafeAtomicAdd(&agg[(size_t)di * 64 + lane], run);
                        run = 0.f;
                    }
                }
            }
        }
    }
}

// ---------------------------------------------------------------------------
// head MFMA kernel (original edge order; ea is fp32).
// ---------------------------------------------------------------------------
__global__ __launch_bounds__(256) void head_mfma(
    const ushort* __restrict__ hb, const int* __restrict__ src,
    const int* __restrict__ dst, const float* __restrict__ ea,
    const ushort* __restrict__ Wh1, const ushort* __restrict__ Wh2b,
    const float* __restrict__ hb1, const float* __restrict__ hb2p,
    float* __restrict__ out, int E, int nchunks) {
    __shared__ char lds[4 * SLABSZ + 4 * HIDSZ];
    int tid = threadIdx.x;
    int w = tid >> 6, lane = tid & 63;
    int quad = lane >> 4, nrow = lane & 15;
    char* slab = lds + w * SLABSZ;
    char* hidb = lds + 4 * SLABSZ + w * HIDSZ;

    bf16x8 wf1[4][4], wfea[4], wh2[2];
    float b1v[4];
#pragma unroll
    for (int nt = 0; nt < 4; nt++) {
        int n = nt * 16 + nrow;
#pragma unroll
        for (int ks = 0; ks < 4; ks++)
            wf1[nt][ks] = *(const bf16x8*)(Wh1 + n * 160 + ks * 32 + quad * 8);
        wfea[nt] = *(const bf16x8*)(Wh1 + n * 160 + 128 + quad * 8);
        b1v[nt] = hb1[n];
    }
#pragma unroll
    for (int ks = 0; ks < 2; ks++)
        wh2[ks] = *(const bf16x8*)(Wh2b + nrow * 64 + ks * 32 + quad * 8);
    float hb2 = hb2p[0];

    for (int chunk = blockIdx.x; chunk < nchunks; chunk += gridDim.x) {
        int ebase = chunk * CHUNK;
        {
            int el = tid >> 1, half = tid & 1;
            int r = el & 31;
            int ec = min(ebase + el, E - 1);
            int node = half ? dst[ec] : src[ec];
            const float4* hrow = (const float4*)(hb + (size_t)node * 64);
            float4* xw = (float4*)(slab + r * XSTRIDE + half * 128);
#pragma unroll
            for (int i = 0; i < 8; i++) xw[i] = hrow[i];
        }
        bf16x8 ea0 = {0, 0, 0, 0, 0, 0, 0, 0};
        bf16x8 ea1 = {0, 0, 0, 0, 0, 0, 0, 0};
        if (quad == 0) {
            int ec0 = min(ebase + w * 32 + nrow, E - 1);
            int ec1 = min(ebase + w * 32 + 16 + nrow, E - 1);
            float4 e0 = ((const float4*)ea)[ec0];
            float4 e1 = ((const float4*)ea)[ec1];
            ushort4 u0, u1;
            u0.x = f2bf(e0.x); u0.y = f2bf(e0.y); u0.z = f2bf(e0.z); u0.w = f2bf(e0.w);
            u1.x = f2bf(e1.x); u1.y = f2bf(e1.y); u1.z = f2bf(e1.z); u1.w = f2bf(e1.w);
            *(ushort4*)&ea0 = u0;
            *(ushort4*)&ea1 = u1;
        }
        f32x4 acc1[2][4];
#pragma unroll
        for (int mt = 0; mt < 2; mt++)
#pragma unroll
            for (int nt = 0; nt < 4; nt++) {
                f32x4 v;
                v[0] = v[1] = v[2] = v[3] = b1v[nt];
                acc1[mt][nt] = v;
            }
#pragma unroll
        for (int ks = 0; ks < 4; ks++) {
            bf16x8 a0 = *(const bf16x8*)(slab + nrow * XSTRIDE + ks * 64 + quad * 16);
            bf16x8 a1 = *(const bf16x8*)(slab + (16 + nrow) * XSTRIDE + ks * 64 + quad * 16);
#pragma unroll
            for (int nt = 0; nt < 4; nt++) {
                acc1[0][nt] = MFMA16(a0, wf1[nt][ks], acc1[0][nt]);
                acc1[1][nt] = MFMA16(a1, wf1[nt][ks], acc1[1][nt]);
            }
        }
#pragma unroll
        for (int nt = 0; nt < 4; nt++) {
            acc1[0][nt] = MFMA16(ea0, wfea[nt], acc1[0][nt]);
            acc1[1][nt] = MFMA16(ea1, wfea[nt], acc1[1][nt]);
        }
#pragma unroll
        for (int mt = 0; mt < 2; mt++)
#pragma unroll
            for (int nt = 0; nt < 4; nt++)
#pragma unroll
                for (int rg = 0; rg < 4; rg++) {
                    float v = acc1[mt][nt][rg];
                    v = v * fast_sig(v);
                    int rm = mt * 16 + quad * 4 + rg;
                    *(ushort*)(hidb + rm * HSTRIDE + (nt * 16 + nrow) * 2) = f2bf(v);
                }
        f32x4 acc3[2];
#pragma unroll
        for (int mt = 0; mt < 2; mt++) {
            f32x4 v;
            v[0] = v[1] = v[2] = v[3] = 0.f;
            acc3[mt] = v;
        }
#pragma unroll
        for (int ks = 0; ks < 2; ks++) {
            bf16x8 a0 = *(const bf16x8*)(hidb + nrow * HSTRIDE + ks * 64 + quad * 16);
            bf16x8 a1 = *(const bf16x8*)(hidb + (16 + nrow) * HSTRIDE + ks * 64 + quad * 16);
            acc3[0] = MFMA16(a0, wh2[ks], acc3[0]);
            acc3[1] = MFMA16(a1, wh2[ks], acc3[1]);
        }
        if (nrow == 0) {
#pragma unroll
            for (int mt = 0; mt < 2; mt++)
#pragma unroll
                for (int rg = 0; rg < 4; rg++) {
                    int e = ebase + w * 32 + mt * 16 + quad * 4 + rg;
                    if (e < E) out[e] = fast_sig(acc3[mt][rg] + hb2);
                }
        }
    }
}

// ---------------------------------------------------------------------------
// GRU MFMA kernel + self-zeroing of agg for the next layer.
// ---------------------------------------------------------------------------
__device__ __forceinline__ bf16x8 aggfrag(const float* __restrict__ row, int off) {
    float4 f0 = *(const float4*)(row + off);
    float4 f1 = *(const float4*)(row + off + 4);
    bf16x8 r;
    r[0] = (short)f2bf(f0.x); r[1] = (short)f2bf(f0.y);
    r[2] = (short)f2bf(f0.z); r[3] = (short)f2bf(f0.w);
    r[4] = (short)f2bf(f1.x); r[5] = (short)f2bf(f1.y);
    r[6] = (short)f2bf(f1.z); r[7] = (short)f2bf(f1.w);
    return r;
}

__global__ __launch_bounds__(256) void gru_mfma(
    float* __restrict__ h, ushort* __restrict__ hb, float* __restrict__ agg,
    const ushort* __restrict__ Wrzg, const ushort* __restrict__ Wnig,
    const ushort* __restrict__ Wnhg,
    const float* __restrict__ bih, const float* __restrict__ bhh, int N) {
    __shared__ char lds[128 * WRZST + 2 * 64 * WNST];  // 51200 B
    int tid = threadIdx.x, w = tid >> 6, lane = tid & 63;
    int quad = lane >> 4, nrow = lane & 15;
    char* wrz = lds;
    char* wni = lds + 128 * WRZST;
    char* wnh = wni + 64 * WNST;

    {
        int r = tid >> 1, half = tid & 1;
        const uint4* g = (const uint4*)(Wrzg + r * 128 + half * 64);
        uint4* d = (uint4*)(wrz + r * WRZST + half * 128);
#pragma unroll
        for (int i = 0; i < 8; i++) d[i] = g[i];
        if (tid < 128) {
            const uint4* g2 = (const uint4*)(Wnig + (tid >> 1) * 64 + (tid & 1) * 32);
            uint4* d2 = (uint4*)(wni + (tid >> 1) * WNST + (tid & 1) * 64);
#pragma unroll
            for (int i = 0; i < 4; i++) d2[i] = g2[i];
        } else {
            int t2 = tid - 128;
            const uint4* g2 = (const uint4*)(Wnhg + (t2 >> 1) * 64 + (t2 & 1) * 32);
            uint4* d2 = (uint4*)(wnh + (t2 >> 1) * WNST + (t2 & 1) * 64);
#pragma unroll
            for (int i = 0; i < 4; i++) d2[i] = g2[i];
        }
    }
    __syncthreads();

    int nb0 = blockIdx.x * 128 + w * 32;
    if (nb0 >= N) return;

    float brz[8], bi[4], bhv[4];
#pragma unroll
    for (int nt = 0; nt < 8; nt++) brz[nt] = bih[nt * 16 + nrow] + bhh[nt * 16 + nrow];
#pragma unroll
    for (int nt = 0; nt < 4; nt++) {
        bi[nt] = bih[128 + nt * 16 + nrow];
        bhv[nt] = bhh[128 + nt * 16 + nrow];
    }

    int n0 = min(nb0 + nrow, N - 1);
    int n1 = min(nb0 + 16 + nrow, N - 1);
    const float* ag0 = agg + (size_t)n0 * 64;
    const float* ag1 = agg + (size_t)n1 * 64;
    const ushort* hb0 = hb + (size_t)n0 * 64;
    const ushort* hb1 = hb + (size_t)n1 * 64;

    f32x4 accrz[2][8], acci[2][4], acch[2][4];
#pragma unroll
    for (int nt = 0; nt < 8; nt++) {
        f32x4 v; v[0] = v[1] = v[2] = v[3] = brz[nt];
        accrz[0][nt] = v; accrz[1][nt] = v;
    }
#pragma unroll
    for (int nt = 0; nt < 4; nt++) {
        f32x4 vi; vi[0] = vi[1] = vi[2] = vi[3] = bi[nt];
        acci[0][nt] = vi; acci[1][nt] = vi;
        f32x4 vh; vh[0] = vh[1] = vh[2] = vh[3] = bhv[nt];
        acch[0][nt] = vh; acch[1][nt] = vh;
    }

#pragma unroll
    for (int ks = 0; ks < 4; ks++) {
        bf16x8 a0, a1;
        if (ks < 2) {
            a0 = aggfrag(ag0, ks * 32 + quad * 8);
            a1 = aggfrag(ag1, ks * 32 + quad * 8);
        } else {
            a0 = *(const bf16x8*)(hb0 + (ks - 2) * 32 + quad * 8);
            a1 = *(const bf16x8*)(hb1 + (ks - 2) * 32 + quad * 8);
        }
#pragma unroll
        for (int nt = 0; nt < 8; nt++) {
            bf16x8 b = *(const bf16x8*)(wrz + (nt * 16 + nrow) * WRZST + ks * 64 + quad * 16);
            accrz[0][nt] = MFMA16(a0, b, accrz[0][nt]);
            accrz[1][nt] = MFMA16(a1, b, accrz[1][nt]);
        }
        if (ks < 2) {
#pragma unroll
            for (int nt = 0; nt < 4; nt++) {
                bf16x8 b = *(const bf16x8*)(wni + (nt * 16 + nrow) * WNST + ks * 64 + quad * 16);
                acci[0][nt] = MFMA16(a0, b, acci[0][nt]);
                acci[1][nt] = MFMA16(a1, b, acci[1][nt]);
            }
        } else {
#pragma unroll
            for (int nt = 0; nt < 4; nt++) {
                bf16x8 b = *(const bf16x8*)(wnh + (nt * 16 + nrow) * WNST + (ks - 2) * 64 + quad * 16);
                acch[0][nt] = MFMA16(a0, b, acch[0][nt]);
                acch[1][nt] = MFMA16(a1, b, acch[1][nt]);
            }
        }
    }

    // gates + h update (C-layout elementwise)
#pragma unroll
    for (int mt = 0; mt < 2; mt++)
#pragma unroll
        for (int nt = 0; nt < 4; nt++)
#pragma unroll
            for (int rg = 0; rg < 4; rg++) {
                int node = nb0 + mt * 16 + quad * 4 + rg;
                if (node < N) {
                    int col = nt * 16 + nrow;
                    float r = fast_sig(accrz[mt][nt][rg]);
                    float z = fast_sig(accrz[mt][nt + 4][rg]);
                    float nn = fast_tanh(acci[mt][nt][rg] + r * acch[mt][nt][rg]);
                    size_t idx = (size_t)node * 64 + col;
                    float ho = h[idx];
                    float hnew = (1.f - z) * nn + z * ho;
                    h[idx] = hnew;
                    hb[idx] = f2bf(hnew);
                }
            }

    // zero this wave's OWN agg rows for the next layer (rows exclusively owned)
    {
        float4 z4 = {0.f, 0.f, 0.f, 0.f};
        if (nb0 + nrow < N) {
            float* a = agg + (size_t)(nb0 + nrow) * 64;
            *(float4*)(a + quad * 8) = z4;
            *(float4*)(a + quad * 8 + 4) = z4;
            *(float4*)(a + 32 + quad * 8) = z4;
            *(float4*)(a + 32 + quad * 8 + 4) = z4;
        }
        if (nb0 + 16 + nrow < N) {
            float* a = agg + (size_t)(nb0 + 16 + nrow) * 64;
            *(float4*)(a + quad * 8) = z4;
            *(float4*)(a + quad * 8 + 4) = z4;
            *(float4*)(a + 32 + quad * 8) = z4;
            *(float4*)(a + 32 + quad * 8 + 4) = z4;
        }
    }
}

extern "C" void kernel_launch(void* const* d_in, const int* in_sizes, int n_in,
                              void* d_out, int out_size, void* d_ws, size_t ws_size,
                              hipStream_t stream) {
    const int* edge_index = (const int*)d_in[0];
    int E = in_sizes[0] / 2;
    const int* src = edge_index;
    const int* dst = edge_index + E;
    const int* kinds = (const int*)d_in[1];
    int N = in_sizes[1];
    const float* edge_attr = (const float*)d_in[2];
    const float* emb = (const float*)d_in[3];
    const float* msg_w1 = (const float*)d_in[4];
    const float* msg_b1 = (const float*)d_in[5];
    const float* msg_w2 = (const float*)d_in[6];
    const float* msg_b2 = (const float*)d_in[7];
    const float* gru_wih = (const float*)d_in[8];
    const float* gru_whh = (const float*)d_in[9];
    const float* gru_bih = (const float*)d_in[10];
    const float* gru_bhh = (const float*)d_in[11];
    const float* head_w1 = (const float*)d_in[12];
    const float* head_b1 = (const float*)d_in[13];
    const float* head_w2 = (const float*)d_in[14];
    const float* head_b2 = (const float*)d_in[15];
    float* out = (float*)d_out;

    // workspace carve-up
    char* p = (char*)d_ws;
    float* h = (float*)p;        p += (size_t)N * 64 * 4;
    float* agg = (float*)p;      p += (size_t)N * 64 * 4;
    int* deg = (int*)p;          p += (size_t)N * 4;
    int* cursor = (int*)p;       p += (size_t)N * 4;
    int* src_s = (int*)p;        p += (size_t)E * 4;
    int* dst_s = (int*)p;        p += (size_t)E * 4;
    ushort* hb = (ushort*)p;     p += (size_t)N * 64 * 2;
    ushort* Wb1 = (ushort*)p;    p += 30720 * 2;
    ushort* Wb2 = (ushort*)p;    p += 12288 * 2;
    ushort* Wh1 = (ushort*)p;    p += 10240 * 2;
    ushort* Wh2b = (ushort*)p;   p += 1024 * 2;
    ushort* Wrz = (ushort*)p;    p += 49152 * 2;
    ushort* Wni = (ushort*)p;    p += 12288 * 2;
    ushort* Wnh = (ushort*)p;    p += 12288 * 2;
    ushort* ea_sb = (ushort*)p;  p += (size_t)E * 4 * 2;

    int nchunks = (E + CHUNK - 1) / CHUNK;

    prep_kernel<<<500, 256, 0, stream>>>(msg_w1, msg_w2, gru_wih, gru_whh, head_w1,
                                         head_w2, Wb1, Wb2, Wh1, Wh2b, Wrz, Wni, Wnh);
    embed_kernel<<<(N * 64 + 255) / 256, 256, 0, stream>>>(h, hb, emb, kinds, N);

    hipMemsetAsync(deg, 0, (size_t)N * sizeof(int), stream);
    hipMemsetAsync(agg, 0, (size_t)N * 64 * sizeof(float), stream);
    hist_kernel<<<(E + 255) / 256, 256, 0, stream>>>(dst, deg, E);
    scan_kernel<<<1, 1024, 0, stream>>>(deg, cursor, N);
    scatter_kernel<<<(E + 255) / 256, 256, 0, stream>>>(src, dst, edge_attr, cursor,
                                                        src_s, dst_s, ea_sb, E);

    for (int l = 0; l < 3; l++) {
        edge_msg_mfma<<<768, 256, 0, stream>>>(
            hb, src_s, dst_s, ea_sb,
            Wb1 + l * 10240, Wb2 + l * 4096,
            msg_b1 + l * 64, msg_b2 + l * 64, agg, E, nchunks);
        gru_mfma<<<(N + 127) / 128, 256, 0, stream>>>(
            h, hb, agg, Wrz + l * 16384, Wni + l * 4096, Wnh + l * 4096,
            gru_bih + l * 192, gru_bhh + l * 192, N);
    }
    head_mfma<<<768, 256, 0, stream>>>(hb, src, dst, edge_attr, Wh1, Wh2b,
                                       head_b1, head_b2, out, E, nchunks);
}